// Round 13
// baseline (63.052 us; speedup 1.0000x reference)
//
#include <hip/hip_runtime.h>
#include <math.h>

constexpr int M_TOK = 8;
constexpr int N_OUT = 8192;
constexpr int K_IN  = 8192;
constexpr int KG    = 64;   // K / G, G = 128
constexpr int R_N   = 4;    // output rows per wave
constexpr int SPLIT = 2;    // K split factor
constexpr int KHALF = K_IN / SPLIT;  // 4096

typedef int   i32x4 __attribute__((ext_vector_type(4)));
typedef float f32x4 __attribute__((ext_vector_type(4)));

// ---------------- Kernel 1: per-token symmetric int8 fake-quant ----------------
__global__ __launch_bounds__(1024) void act_quant_kernel(const float* __restrict__ x,
                                                         float* __restrict__ xq) {
    const int row = blockIdx.x;
    const f32x4* xr = reinterpret_cast<const f32x4*>(x + (size_t)row * K_IN);
    f32x4* oq = reinterpret_cast<f32x4*>(xq + (size_t)row * K_IN);
    const int tid = threadIdx.x;

    f32x4 v0 = xr[tid * 2];
    f32x4 v1 = xr[tid * 2 + 1];

    float m = fmaxf(
        fmaxf(fmaxf(fabsf(v0.x), fabsf(v0.y)), fmaxf(fabsf(v0.z), fabsf(v0.w))),
        fmaxf(fmaxf(fabsf(v1.x), fabsf(v1.y)), fmaxf(fabsf(v1.z), fabsf(v1.w))));

    #pragma unroll
    for (int off = 32; off; off >>= 1) m = fmaxf(m, __shfl_xor(m, off));

    __shared__ float smax[16];
    if ((tid & 63) == 0) smax[tid >> 6] = m;
    __syncthreads();
    float mm = smax[0];
    #pragma unroll
    for (int i = 1; i < 16; ++i) mm = fmaxf(mm, smax[i]);

    const float s = fmaxf(mm / 127.0f, 1e-8f);

    auto quant = [&](float v) -> float {
        float q = rintf(v / s);              // numpy round = half-to-even
        q = fminf(fmaxf(q, -127.0f), 127.0f);
        return q * s;
    };

    f32x4 o0, o1;
    o0.x = quant(v0.x); o0.y = quant(v0.y); o0.z = quant(v0.z); o0.w = quant(v0.w);
    o1.x = quant(v1.x); o1.y = quant(v1.y); o1.z = quant(v1.z); o1.w = quant(v1.w);
    oq[tid * 2]     = o0;
    oq[tid * 2 + 1] = o1;
}

// ---------------- Kernel 2: fine-staggered dequant-GEMM, split-K=2 ----------------
// r12 body (fine per-wave k-phase stagger @128 B: 68.5->59.6->56.8 us) with
// split-K=2 re-tested POST-stagger: 1024 blocks -> 4 waves/SIMD. r4's null was
// measured while the channel wall masked latency effects.
// Ledger: burst-group (r11), LDS-DMA dbuf (r10), nt (r8), VGPR rotate (r3)
// REGRESSED; xq-LDS (r5), fusion (r6), gload_lds (r7) NULL pre-stagger.
__global__ __launch_bounds__(256) void qlin_kernel(const float* __restrict__ xq,
                                                   const int* __restrict__ qw,
                                                   const float* __restrict__ scales,
                                                   float* __restrict__ partial) {
    const int wave = blockIdx.x * 4 + (threadIdx.x >> 6);
    const int lane = threadIdx.x & 63;
    const int half = wave & (SPLIT - 1);
    const int n0 = (wave >> 1) * R_N;
    const int kbase = half * KHALF;
    const int lk = lane * 4;
    const int phase = (wave & 127) * 32;   // 128 classes @128 B within the half

    float acc[R_N][M_TOK];
    #pragma unroll
    for (int r = 0; r < R_N; ++r)
        #pragma unroll
        for (int m = 0; m < M_TOK; ++m) acc[r][m] = 0.0f;

    for (int t = 0; t < 16; ++t) {
        const int k = kbase + ((phase + t * 256 + lk) & (KHALF - 1));  // mult of 4
        const int g = k >> 7;  // per-lane group index

        f32x4 xv[M_TOK];
        #pragma unroll
        for (int m = 0; m < M_TOK; ++m)
            xv[m] = *reinterpret_cast<const f32x4*>(xq + (size_t)m * K_IN + k);

        #pragma unroll
        for (int r = 0; r < R_N; ++r) {
            const i32x4 c =
                *reinterpret_cast<const i32x4*>(qw + (size_t)(n0 + r) * K_IN + k);
            const float sc = scales[(size_t)(n0 + r) * KG + g];
            const float w0 = (float)c.x * sc;
            const float w1 = (float)c.y * sc;
            const float w2 = (float)c.z * sc;
            const float w3 = (float)c.w * sc;
            #pragma unroll
            for (int m = 0; m < M_TOK; ++m) {
                float a = acc[r][m];
                a = fmaf(w0, xv[m].x, a);
                a = fmaf(w1, xv[m].y, a);
                a = fmaf(w2, xv[m].z, a);
                a = fmaf(w3, xv[m].w, a);
                acc[r][m] = a;
            }
        }
    }

    // full butterfly reduce -> every lane holds each (r,m) total
    #pragma unroll
    for (int r = 0; r < R_N; ++r)
        #pragma unroll
        for (int m = 0; m < M_TOK; ++m) {
            float v = acc[r][m];
            #pragma unroll
            for (int off = 32; off; off >>= 1) v += __shfl_xor(v, off);
            acc[r][m] = v;
        }

    // lane (r*8 + m) writes partial[half][m][n0+r]
    if (lane < R_N * M_TOK) {
        const int rsel = lane >> 3;
        const int msel = lane & 7;
        float myv = 0.0f;
        #pragma unroll
        for (int r = 0; r < R_N; ++r)
            #pragma unroll
            for (int m = 0; m < M_TOK; ++m)
                if (r == rsel && m == msel) myv = acc[r][m];
        partial[((size_t)half * M_TOK + msel) * N_OUT + n0 + rsel] = myv;
    }
}

// ---------------- Kernel 3: combine split-K partials + bias ----------------
__global__ __launch_bounds__(256) void reduce_kernel(const float* __restrict__ partial,
                                                     const float* __restrict__ bias,
                                                     float* __restrict__ out) {
    const int idx = blockIdx.x * 256 + threadIdx.x;   // f32x4 chunk id, 16384 total
    const int m  = idx >> 11;                          // 2048 chunks per m row
    const int nc = idx & 2047;
    const f32x4* p = reinterpret_cast<const f32x4*>(partial);
    const f32x4 p0 = p[((size_t)0 * M_TOK + m) * 2048 + nc];
    const f32x4 p1 = p[((size_t)1 * M_TOK + m) * 2048 + nc];
    const f32x4 b  = reinterpret_cast<const f32x4*>(bias)[nc];
    f32x4 o;
    o.x = p0.x + p1.x + b.x;
    o.y = p0.y + p1.y + b.y;
    o.z = p0.z + p1.z + b.z;
    o.w = p0.w + p1.w + b.w;
    reinterpret_cast<f32x4*>(out)[(size_t)m * 2048 + nc] = o;
}

extern "C" void kernel_launch(void* const* d_in, const int* in_sizes, int n_in,
                              void* d_out, int out_size, void* d_ws, size_t ws_size,
                              hipStream_t stream) {
    const float* x      = (const float*)d_in[0];
    const int*   qw     = (const int*)d_in[1];
    const float* scales = (const float*)d_in[2];
    const float* bias   = (const float*)d_in[3];
    float* out = (float*)d_out;

    float* partial = (float*)d_ws;                             // SPLIT*M*N floats = 512 KiB
    float* xq      = partial + (size_t)SPLIT * M_TOK * N_OUT;  // M*K floats = 256 KiB

    act_quant_kernel<<<M_TOK, 1024, 0, stream>>>(x, xq);

    const int blocks = (N_OUT / R_N) * SPLIT / 4;   // 1024 blocks x 256 threads
    qlin_kernel<<<blocks, 256, 0, stream>>>(xq, qw, scales, partial);

    reduce_kernel<<<(M_TOK * N_OUT / 4) / 256, 256, 0, stream>>>(partial, bias, out);
}

// Round 14
// 61.678 us; speedup vs baseline: 1.0223x; 1.0223x over previous
//
#include <hip/hip_runtime.h>
#include <math.h>

constexpr int M_TOK = 8;
constexpr int N_OUT = 8192;
constexpr int K_IN  = 8192;
constexpr int KG    = 64;   // K / G, G = 128
constexpr int R_N   = 4;    // output rows per wave

typedef int   i32x4 __attribute__((ext_vector_type(4)));
typedef float f32x4 __attribute__((ext_vector_type(4)));

// async global->LDS DMA, 16 B per lane (global_load_lds_dwordx4).
// LDS dest linear: wave-uniform base + lane*16. Counted by vmcnt.
__device__ __forceinline__ void gload_lds16(const void* g, void* l) {
    __builtin_amdgcn_global_load_lds(
        (const __attribute__((address_space(1))) void*)g,
        (__attribute__((address_space(3))) void*)l, 16, 0, 0);
}

// ---------------- Kernel 1: per-token symmetric int8 fake-quant ----------------
__global__ __launch_bounds__(1024) void act_quant_kernel(const float* __restrict__ x,
                                                         float* __restrict__ xq) {
    const int row = blockIdx.x;
    const f32x4* xr = reinterpret_cast<const f32x4*>(x + (size_t)row * K_IN);
    f32x4* oq = reinterpret_cast<f32x4*>(xq + (size_t)row * K_IN);
    const int tid = threadIdx.x;

    f32x4 v0 = xr[tid * 2];
    f32x4 v1 = xr[tid * 2 + 1];

    float m = fmaxf(
        fmaxf(fmaxf(fabsf(v0.x), fabsf(v0.y)), fmaxf(fabsf(v0.z), fabsf(v0.w))),
        fmaxf(fmaxf(fabsf(v1.x), fabsf(v1.y)), fmaxf(fabsf(v1.z), fabsf(v1.w))));

    #pragma unroll
    for (int off = 32; off; off >>= 1) m = fmaxf(m, __shfl_xor(m, off));

    __shared__ float smax[16];
    if ((tid & 63) == 0) smax[tid >> 6] = m;
    __syncthreads();
    float mm = smax[0];
    #pragma unroll
    for (int i = 1; i < 16; ++i) mm = fmaxf(mm, smax[i]);

    const float s = fmaxf(mm / 127.0f, 1e-8f);

    auto quant = [&](float v) -> float {
        float q = rintf(v / s);              // numpy round = half-to-even
        q = fminf(fmaxf(q, -127.0f), 127.0f);
        return q * s;
    };

    f32x4 o0, o1;
    o0.x = quant(v0.x); o0.y = quant(v0.y); o0.z = quant(v0.z); o0.w = quant(v0.w);
    o1.x = quant(v1.x); o1.y = quant(v1.y); o1.z = quant(v1.z); o1.w = quant(v1.w);
    oq[tid * 2]     = o0;
    oq[tid * 2 + 1] = o1;
}

// ---------------- Kernel 2: fine-staggered GEMM + wave-private LDS prefetch ----------------
// r12 skeleton (fine per-wave stagger @128 B: 56.8 us) + weight prefetch via
// wave-PRIVATE double-buffered global_load_lds: no __syncthreads (r10's
// lockstep killer), no VGPR cost (r3's spill killer). Issue order pinned
// [xv loads] < [next-tile DMA] so the compiler's xv wait is vmcnt(4), leaving
// the 4 prefetch DMAs in flight across the FMA block (cp.async.wait_group
// analog). Ledger: split-K REGRESSED post-stagger (r13); burst-group (r11),
// barrier dbuf (r10), nt (r8), VGPR rotate (r3) REGRESSED; r4-r7 NULL.
__global__ __launch_bounds__(256) void qlin_kernel(const float* __restrict__ xq,
                                                   const int* __restrict__ qw,
                                                   const float* __restrict__ scales,
                                                   const float* __restrict__ bias,
                                                   float* __restrict__ out) {
    __shared__ int wbuf[4][2][R_N][256];   // per-wave private, 32 KiB total

    const int widx = threadIdx.x >> 6;
    const int lane = threadIdx.x & 63;
    const int wave = blockIdx.x * 4 + widx;
    const int n0 = wave * R_N;
    const int lk = lane * 4;
    const int phase = (wave & 255) * 32;   // 256 classes, 128 B granularity

    float acc[R_N][M_TOK];
    #pragma unroll
    for (int r = 0; r < R_N; ++r)
        #pragma unroll
        for (int m = 0; m < M_TOK; ++m) acc[r][m] = 0.0f;

    auto dma = [&](int buf, int t) {
        const int k = (phase + t * 256 + lk) & (K_IN - 1);
        #pragma unroll
        for (int r = 0; r < R_N; ++r)
            gload_lds16(qw + (size_t)(n0 + r) * K_IN + k,
                        &wbuf[widx][buf][r][lk]);
    };

    dma(0, 0);
    asm volatile("s_waitcnt vmcnt(0)" ::: "memory");

    int buf = 0;
    for (int t = 0; t < 32; ++t) {
        const int k = (phase + t * 256 + lk) & (K_IN - 1);  // mult of 4
        const int g = k >> 7;   // per-lane scale-group index

        // 1) issue xq loads (L2-hot)
        f32x4 xv[M_TOK];
        #pragma unroll
        for (int m = 0; m < M_TOK; ++m)
            xv[m] = *reinterpret_cast<const f32x4*>(xq + (size_t)m * K_IN + k);

        __builtin_amdgcn_sched_barrier(0);   // pin: xv issued before DMA

        // 2) issue next tile's weight DMA (stays in flight across compute)
        if (t + 1 < 32) dma(buf ^ 1, t + 1);

        // 3) wait: everything except the 4 newest (the prefetch DMAs)
        asm volatile("s_waitcnt vmcnt(4)" ::: "memory");
        __builtin_amdgcn_sched_barrier(0);   // no ds_read hoist above the wait

        // 4) compute from current LDS buffer
        #pragma unroll
        for (int r = 0; r < R_N; ++r) {
            const i32x4 c = *reinterpret_cast<const i32x4*>(&wbuf[widx][buf][r][lk]);
            const float sc = scales[(size_t)(n0 + r) * KG + g];
            const float w0 = (float)c.x * sc;
            const float w1 = (float)c.y * sc;
            const float w2 = (float)c.z * sc;
            const float w3 = (float)c.w * sc;
            #pragma unroll
            for (int m = 0; m < M_TOK; ++m) {
                float a = acc[r][m];
                a = fmaf(w0, xv[m].x, a);
                a = fmaf(w1, xv[m].y, a);
                a = fmaf(w2, xv[m].z, a);
                a = fmaf(w3, xv[m].w, a);
                acc[r][m] = a;
            }
        }

        buf ^= 1;
    }

    // full butterfly reduce -> every lane holds each (r,m) total
    #pragma unroll
    for (int r = 0; r < R_N; ++r)
        #pragma unroll
        for (int m = 0; m < M_TOK; ++m) {
            float v = acc[r][m];
            #pragma unroll
            for (int off = 32; off; off >>= 1) v += __shfl_xor(v, off);
            acc[r][m] = v;
        }

    // lane (r*8 + m) writes out[m][n0+r]
    if (lane < R_N * M_TOK) {
        const int rsel = lane >> 3;
        const int msel = lane & 7;
        float myv = 0.0f;
        #pragma unroll
        for (int r = 0; r < R_N; ++r)
            #pragma unroll
            for (int m = 0; m < M_TOK; ++m)
                if (r == rsel && m == msel) myv = acc[r][m];
        out[(size_t)msel * N_OUT + n0 + rsel] = myv + bias[n0 + rsel];
    }
}

extern "C" void kernel_launch(void* const* d_in, const int* in_sizes, int n_in,
                              void* d_out, int out_size, void* d_ws, size_t ws_size,
                              hipStream_t stream) {
    const float* x      = (const float*)d_in[0];
    const int*   qw     = (const int*)d_in[1];
    const float* scales = (const float*)d_in[2];
    const float* bias   = (const float*)d_in[3];
    float* out = (float*)d_out;
    float* xq  = (float*)d_ws;  // M*K floats = 256 KiB scratch

    act_quant_kernel<<<M_TOK, 1024, 0, stream>>>(x, xq);

    const int waves  = N_OUT / R_N;        // 2048
    const int blocks = waves / 4;          // 512 blocks x 256 threads
    qlin_kernel<<<blocks, 256, 0, stream>>>(xq, qw, scales, bias, out);
}

// Round 15
// 55.187 us; speedup vs baseline: 1.1425x; 1.1176x over previous
//
#include <hip/hip_runtime.h>
#include <math.h>

constexpr int M_TOK = 8;
constexpr int N_OUT = 8192;
constexpr int K_IN  = 8192;
constexpr int KG    = 64;   // K / G, G = 128
constexpr int R_N   = 4;    // output rows per wave

typedef int   i32x4 __attribute__((ext_vector_type(4)));
typedef float f32x4 __attribute__((ext_vector_type(4)));

// ---------------- Kernel 1: per-token int8 quant -> int8 CODES + per-row scale ----------------
// Codes are exact (integers in [-127,127]); dequant scale s_m factors out of
// the whole dot product, applied once in the epilogue of kernel 2.
__global__ __launch_bounds__(1024) void act_quant_kernel(const float* __restrict__ x,
                                                         signed char* __restrict__ xq8,
                                                         float* __restrict__ srow) {
    const int row = blockIdx.x;
    const f32x4* xr = reinterpret_cast<const f32x4*>(x + (size_t)row * K_IN);
    const int tid = threadIdx.x;

    f32x4 v0 = xr[tid * 2];
    f32x4 v1 = xr[tid * 2 + 1];

    float m = fmaxf(
        fmaxf(fmaxf(fabsf(v0.x), fabsf(v0.y)), fmaxf(fabsf(v0.z), fabsf(v0.w))),
        fmaxf(fmaxf(fabsf(v1.x), fabsf(v1.y)), fmaxf(fabsf(v1.z), fabsf(v1.w))));

    #pragma unroll
    for (int off = 32; off; off >>= 1) m = fmaxf(m, __shfl_xor(m, off));

    __shared__ float smax[16];
    if ((tid & 63) == 0) smax[tid >> 6] = m;
    __syncthreads();
    float mm = smax[0];
    #pragma unroll
    for (int i = 1; i < 16; ++i) mm = fmaxf(mm, smax[i]);

    const float s = fmaxf(mm / 127.0f, 1e-8f);   // numpy: true div, clamp
    if (tid == 0) srow[row] = s;

    auto qcode = [&](float v) -> int {
        float q = rintf(v / s);              // numpy round = half-to-even
        q = fminf(fmaxf(q, -127.0f), 127.0f);
        return (int)q;
    };

    const int q0 = qcode(v0.x) & 255, q1 = qcode(v0.y) & 255,
              q2 = qcode(v0.z) & 255, q3 = qcode(v0.w) & 255;
    const int q4 = qcode(v1.x) & 255, q5 = qcode(v1.y) & 255,
              q6 = qcode(v1.z) & 255, q7 = qcode(v1.w) & 255;
    int2 p;
    p.x = q0 | (q1 << 8) | (q2 << 16) | (q3 << 24);
    p.y = q4 | (q5 << 8) | (q6 << 16) | (q7 << 24);
    reinterpret_cast<int2*>(xq8 + (size_t)row * K_IN)[tid] = p;
}

// ---------------- Kernel 2: staggered dequant-GEMM, activations resident in LDS ----------------
// r12 skeleton (fine per-wave k-stagger @128 B: 56.8 us). Single structural
// change: the 8x8192 int8 activation codes (64 KiB) are loaded into LDS ONCE
// (one barrier), then the main loop's ONLY global traffic is the weight
// stream - no xq VMEM ops sharing the vmcnt FIFO, no L2 re-reads. Unpack is
// bfe+cvt per element; per-token scale applied in the epilogue (factors out).
// Ledger: re-timing same streams always lost (r3/r10/r11/r13/r14); only
// stream-set changes won (r9/r12 stagger). This deletes a stream class.
__global__ __launch_bounds__(256) void qlin_kernel(const signed char* __restrict__ xq8,
                                                   const float* __restrict__ srow,
                                                   const int* __restrict__ qw,
                                                   const float* __restrict__ scales,
                                                   const float* __restrict__ bias,
                                                   float* __restrict__ out) {
    __shared__ int xsm[M_TOK * K_IN / 4];   // 64 KiB of int8 codes

    const int widx = threadIdx.x >> 6;
    const int lane = threadIdx.x & 63;
    const int wave = blockIdx.x * 4 + widx;
    const int n0 = wave * R_N;
    const int lk = lane * 4;
    const int phase = (wave & 255) * 32;   // 256 classes, 128 B granularity

    // one-time cooperative LDS fill: 4096 i32x4 chunks / 256 threads = 16 each
    {
        const i32x4* src = reinterpret_cast<const i32x4*>(xq8);
        i32x4* dst = reinterpret_cast<i32x4*>(xsm);
        #pragma unroll
        for (int j = 0; j < 16; ++j)
            dst[j * 256 + threadIdx.x] = src[j * 256 + threadIdx.x];
    }
    __syncthreads();   // only barrier; loop below is free-running

    float acc[R_N][M_TOK];
    #pragma unroll
    for (int r = 0; r < R_N; ++r)
        #pragma unroll
        for (int m = 0; m < M_TOK; ++m) acc[r][m] = 0.0f;

    for (int t = 0; t < 32; ++t) {
        const int k = (phase + t * 256 + lk) & (K_IN - 1);  // mult of 4
        const int g = k >> 7;   // per-lane scale-group index
        const int kd = k >> 2;  // dword index within a row

        // unpack activation codes from LDS: q exact, scale deferred to epilogue
        f32x4 xv[M_TOK];
        #pragma unroll
        for (int m = 0; m < M_TOK; ++m) {
            const int d = xsm[m * 2048 + kd];
            xv[m].x = (float)((d << 24) >> 24);
            xv[m].y = (float)((d << 16) >> 24);
            xv[m].z = (float)((d << 8) >> 24);
            xv[m].w = (float)(d >> 24);
        }

        #pragma unroll
        for (int r = 0; r < R_N; ++r) {
            const i32x4 c =
                *reinterpret_cast<const i32x4*>(qw + (size_t)(n0 + r) * K_IN + k);
            const float sc = scales[(size_t)(n0 + r) * KG + g];
            const float w0 = (float)c.x * sc;
            const float w1 = (float)c.y * sc;
            const float w2 = (float)c.z * sc;
            const float w3 = (float)c.w * sc;
            #pragma unroll
            for (int m = 0; m < M_TOK; ++m) {
                float a = acc[r][m];
                a = fmaf(w0, xv[m].x, a);
                a = fmaf(w1, xv[m].y, a);
                a = fmaf(w2, xv[m].z, a);
                a = fmaf(w3, xv[m].w, a);
                acc[r][m] = a;
            }
        }
    }

    // full butterfly reduce -> every lane holds each (r,m) total
    #pragma unroll
    for (int r = 0; r < R_N; ++r)
        #pragma unroll
        for (int m = 0; m < M_TOK; ++m) {
            float v = acc[r][m];
            #pragma unroll
            for (int off = 32; off; off >>= 1) v += __shfl_xor(v, off);
            acc[r][m] = v;
        }

    // lane (r*8 + m) writes out[m][n0+r] = s_m * acc + bias  (static-index chain)
    if (lane < R_N * M_TOK) {
        const int rsel = lane >> 3;
        const int msel = lane & 7;
        float myv = 0.0f;
        #pragma unroll
        for (int r = 0; r < R_N; ++r)
            #pragma unroll
            for (int m = 0; m < M_TOK; ++m)
                if (r == rsel && m == msel) myv = acc[r][m] * srow[m];
        out[(size_t)msel * N_OUT + n0 + rsel] = myv + bias[n0 + rsel];
    }
}

extern "C" void kernel_launch(void* const* d_in, const int* in_sizes, int n_in,
                              void* d_out, int out_size, void* d_ws, size_t ws_size,
                              hipStream_t stream) {
    const float* x      = (const float*)d_in[0];
    const int*   qw     = (const int*)d_in[1];
    const float* scales = (const float*)d_in[2];
    const float* bias   = (const float*)d_in[3];
    float* out = (float*)d_out;

    float*       srow = (float*)d_ws;                       // 8 floats (pad to 256 B)
    signed char* xq8  = (signed char*)d_ws + 256;           // M*K int8 = 64 KiB

    act_quant_kernel<<<M_TOK, 1024, 0, stream>>>(x, xq8, srow);

    const int waves  = N_OUT / R_N;        // 2048
    const int blocks = waves / 4;          // 512 blocks x 256 threads
    qlin_kernel<<<blocks, 256, 0, stream>>>(xq8, srow, qw, scales, bias, out);
}

// Round 16
// 54.388 us; speedup vs baseline: 1.1593x; 1.0147x over previous
//
#include <hip/hip_runtime.h>
#include <math.h>

constexpr int M_TOK = 8;
constexpr int N_OUT = 8192;
constexpr int K_IN  = 8192;
constexpr int KG    = 64;   // K / G, G = 128
constexpr int R_N   = 4;    // output rows per wave

typedef int   i32x4 __attribute__((ext_vector_type(4)));
typedef float f32x4 __attribute__((ext_vector_type(4)));

// ---------------- Kernel 1: per-token int8 quant -> int8 CODES + per-row scale ----------------
__global__ __launch_bounds__(1024) void act_quant_kernel(const float* __restrict__ x,
                                                         signed char* __restrict__ xq8,
                                                         float* __restrict__ srow) {
    const int row = blockIdx.x;
    const f32x4* xr = reinterpret_cast<const f32x4*>(x + (size_t)row * K_IN);
    const int tid = threadIdx.x;

    f32x4 v0 = xr[tid * 2];
    f32x4 v1 = xr[tid * 2 + 1];

    float m = fmaxf(
        fmaxf(fmaxf(fabsf(v0.x), fabsf(v0.y)), fmaxf(fabsf(v0.z), fabsf(v0.w))),
        fmaxf(fmaxf(fabsf(v1.x), fabsf(v1.y)), fmaxf(fabsf(v1.z), fabsf(v1.w))));

    #pragma unroll
    for (int off = 32; off; off >>= 1) m = fmaxf(m, __shfl_xor(m, off));

    __shared__ float smax[16];
    if ((tid & 63) == 0) smax[tid >> 6] = m;
    __syncthreads();
    float mm = smax[0];
    #pragma unroll
    for (int i = 1; i < 16; ++i) mm = fmaxf(mm, smax[i]);

    const float s = fmaxf(mm / 127.0f, 1e-8f);   // numpy: true div, clamp
    if (tid == 0) srow[row] = s;

    auto qcode = [&](float v) -> int {
        float q = rintf(v / s);              // numpy round = half-to-even
        q = fminf(fmaxf(q, -127.0f), 127.0f);
        return (int)q;
    };

    const int q0 = qcode(v0.x) & 255, q1 = qcode(v0.y) & 255,
              q2 = qcode(v0.z) & 255, q3 = qcode(v0.w) & 255;
    const int q4 = qcode(v1.x) & 255, q5 = qcode(v1.y) & 255,
              q6 = qcode(v1.z) & 255, q7 = qcode(v1.w) & 255;
    int2 p;
    p.x = q0 | (q1 << 8) | (q2 << 16) | (q3 << 24);
    p.y = q4 | (q5 << 8) | (q6 << 16) | (q7 << 24);
    reinterpret_cast<int2*>(xq8 + (size_t)row * K_IN)[tid] = p;
}

// ---------------- Kernel 2: staggered dequant-GEMM, activations resident in LDS ----------------
// r15 skeleton (LDS-resident int8 activation codes; weights are the ONLY
// global stream: 55.2 us). Single change: stagger refined from 256 classes
// @128 B (8 waves exactly in-phase per class) to UNIQUE per-wave phase @16 B
// (2048 classes, cohort size 1). Chunks stay 16 B aligned; consecutive t's
// are contiguous so edge lines are reused by the same wave.
// Ledger of wins: stagger 32@1KiB (r9, -9 us), 256@128B (r12, -2.8), LDS codes
// (r15, -1.6). REGRESSED: VGPR rotate (r3), nt (r8), barrier dbuf (r10),
// burst-group (r11), split-K post-stagger (r13), wave-private vmcnt pf (r14).
__global__ __launch_bounds__(256) void qlin_kernel(const signed char* __restrict__ xq8,
                                                   const float* __restrict__ srow,
                                                   const int* __restrict__ qw,
                                                   const float* __restrict__ scales,
                                                   const float* __restrict__ bias,
                                                   float* __restrict__ out) {
    __shared__ int xsm[M_TOK * K_IN / 4];   // 64 KiB of int8 codes

    const int widx = threadIdx.x >> 6;
    const int lane = threadIdx.x & 63;
    const int wave = blockIdx.x * 4 + widx;
    const int n0 = wave * R_N;
    const int lk = lane * 4;
    const int phase = (wave * 4) & (K_IN - 1);   // unique per-wave, 16 B granularity

    // one-time cooperative LDS fill: 4096 i32x4 chunks / 256 threads = 16 each
    {
        const i32x4* src = reinterpret_cast<const i32x4*>(xq8);
        i32x4* dst = reinterpret_cast<i32x4*>(xsm);
        #pragma unroll
        for (int j = 0; j < 16; ++j)
            dst[j * 256 + threadIdx.x] = src[j * 256 + threadIdx.x];
    }
    __syncthreads();   // only barrier; loop below is free-running

    float acc[R_N][M_TOK];
    #pragma unroll
    for (int r = 0; r < R_N; ++r)
        #pragma unroll
        for (int m = 0; m < M_TOK; ++m) acc[r][m] = 0.0f;

    for (int t = 0; t < 32; ++t) {
        const int k = (phase + t * 256 + lk) & (K_IN - 1);  // mult of 4
        const int g = k >> 7;   // per-lane scale-group index
        const int kd = k >> 2;  // dword index within a row

        // unpack activation codes from LDS: q exact, scale deferred to epilogue
        f32x4 xv[M_TOK];
        #pragma unroll
        for (int m = 0; m < M_TOK; ++m) {
            const int d = xsm[m * 2048 + kd];
            xv[m].x = (float)((d << 24) >> 24);
            xv[m].y = (float)((d << 16) >> 24);
            xv[m].z = (float)((d << 8) >> 24);
            xv[m].w = (float)(d >> 24);
        }

        #pragma unroll
        for (int r = 0; r < R_N; ++r) {
            const i32x4 c =
                *reinterpret_cast<const i32x4*>(qw + (size_t)(n0 + r) * K_IN + k);
            const float sc = scales[(size_t)(n0 + r) * KG + g];
            const float w0 = (float)c.x * sc;
            const float w1 = (float)c.y * sc;
            const float w2 = (float)c.z * sc;
            const float w3 = (float)c.w * sc;
            #pragma unroll
            for (int m = 0; m < M_TOK; ++m) {
                float a = acc[r][m];
                a = fmaf(w0, xv[m].x, a);
                a = fmaf(w1, xv[m].y, a);
                a = fmaf(w2, xv[m].z, a);
                a = fmaf(w3, xv[m].w, a);
                acc[r][m] = a;
            }
        }
    }

    // full butterfly reduce -> every lane holds each (r,m) total
    #pragma unroll
    for (int r = 0; r < R_N; ++r)
        #pragma unroll
        for (int m = 0; m < M_TOK; ++m) {
            float v = acc[r][m];
            #pragma unroll
            for (int off = 32; off; off >>= 1) v += __shfl_xor(v, off);
            acc[r][m] = v;
        }

    // lane (r*8 + m) writes out[m][n0+r] = s_m * acc + bias  (static-index chain)
    if (lane < R_N * M_TOK) {
        const int rsel = lane >> 3;
        const int msel = lane & 7;
        float myv = 0.0f;
        #pragma unroll
        for (int r = 0; r < R_N; ++r)
            #pragma unroll
            for (int m = 0; m < M_TOK; ++m)
                if (r == rsel && m == msel) myv = acc[r][m] * srow[m];
        out[(size_t)msel * N_OUT + n0 + rsel] = myv + bias[n0 + rsel];
    }
}

extern "C" void kernel_launch(void* const* d_in, const int* in_sizes, int n_in,
                              void* d_out, int out_size, void* d_ws, size_t ws_size,
                              hipStream_t stream) {
    const float* x      = (const float*)d_in[0];
    const int*   qw     = (const int*)d_in[1];
    const float* scales = (const float*)d_in[2];
    const float* bias   = (const float*)d_in[3];
    float* out = (float*)d_out;

    float*       srow = (float*)d_ws;                       // 8 floats (pad to 256 B)
    signed char* xq8  = (signed char*)d_ws + 256;           // M*K int8 = 64 KiB

    act_quant_kernel<<<M_TOK, 1024, 0, stream>>>(x, xq8, srow);

    const int waves  = N_OUT / R_N;        // 2048
    const int blocks = waves / 4;          // 512 blocks x 256 threads
    qlin_kernel<<<blocks, 256, 0, stream>>>(xq8, srow, qw, scales, bias, out);
}